// Round 1
// baseline (258.444 us; speedup 1.0000x reference)
//
#include <hip/hip_runtime.h>
#include <math.h>

#define B_ 16
#define S_ 2048
#define IN_DIM 128
#define E2 6
#define E_ 3
#define OUT_DIM 64

// ws layout:
//   [0, B*S*4 floats)  : h padded to float4 (x,y,z,0)        = 524288 B
//   then 64 ints       : per batch {max_d2_bits, total, diag, vert}

__global__ void init_acc(int* acc) {
    int t = threadIdx.x;
    if (t < 64) acc[t] = 0;
}

// one wave per row: 64 lanes x float2 = 128 inputs
__global__ __launch_bounds__(256) void embed_kernel(
    const float* __restrict__ x, const float* __restrict__ w1,
    const float* __restrict__ b1, const float* __restrict__ w2,
    const float* __restrict__ b2, float* __restrict__ hws)
{
    int wave = threadIdx.x >> 6;
    int lane = threadIdx.x & 63;
    int row  = blockIdx.x * 4 + wave;            // [0, B*S)
    const float2* x2 = (const float2*)(x + (size_t)row * IN_DIM);
    float2 xv = x2[lane];
    const float* w1a = w1 + (2 * lane) * E2;     // 12 contiguous floats
    float acc[E2];
#pragma unroll
    for (int j = 0; j < E2; ++j)
        acc[j] = xv.x * w1a[j] + xv.y * w1a[E2 + j];
#pragma unroll
    for (int j = 0; j < E2; ++j) {
#pragma unroll
        for (int off = 32; off >= 1; off >>= 1)
            acc[j] += __shfl_xor(acc[j], off, 64);
    }
    if (lane == 0) {
        float a[E2];
#pragma unroll
        for (int j = 0; j < E2; ++j) a[j] = fmaxf(acc[j] + b1[j], 0.f);
        float h[E_];
#pragma unroll
        for (int e = 0; e < E_; ++e) {
            float s = b2[e];
#pragma unroll
            for (int j = 0; j < E2; ++j) s += a[j] * w2[j * E_ + e];
            h[e] = s;
        }
        ((float4*)hws)[row] = make_float4(h[0], h[1], h[2], 0.f);
    }
}

// grid: B * 32 colTiles * 8 rowBlocks = 4096 blocks of 256
// lane = column j within tile; wave picks a 64-row segment (4 waves x 64 = 256 rows/block)
__global__ __launch_bounds__(256) void max_kernel(
    const float* __restrict__ hws, int* __restrict__ acc)
{
    __shared__ float4 sh[S_];
    int bid = blockIdx.x;
    int b   = bid >> 8;
    int rem = bid & 255;
    int ct  = rem >> 3;
    int rb  = rem & 7;
    const float4* h4 = (const float4*)hws + (size_t)b * S_;
    for (int k = threadIdx.x; k < S_; k += 256) sh[k] = h4[k];
    __syncthreads();
    int lane = threadIdx.x & 63, wave = threadIdx.x >> 6;
    int j = ct * 64 + lane;
    float4 hj = sh[j];
    int s0 = rb * 256 + wave * 64;
    float m = 0.f;
#pragma unroll 8
    for (int s = s0; s < s0 + 64; ++s) {
        float4 hs = sh[s];                       // broadcast, conflict-free
        float dx = hj.x - hs.x, dy = hj.y - hs.y, dz = hj.z - hs.z;
        float d2 = dx * dx + dy * dy + dz * dz;
        m = fmaxf(m, d2);
    }
#pragma unroll
    for (int off = 32; off >= 1; off >>= 1)
        m = fmaxf(m, __shfl_xor(m, off, 64));
    __shared__ float wmax[4];
    if (lane == 0) wmax[wave] = m;
    __syncthreads();
    if (threadIdx.x == 0) {
        float mm = fmaxf(fmaxf(wmax[0], wmax[1]), fmaxf(wmax[2], wmax[3]));
        atomicMax(&acc[b * 4 + 0], __float_as_int(mm));  // d2 >= 0: int order == float order
    }
}

__device__ __forceinline__ unsigned computeR(const float4* sh, int s,
                                             float hx, float hy, float hz, float thr2)
{
    float4 hs = sh[s];
    float dx = hx - hs.x, dy = hy - hs.y, dz = hz - hs.z;
    float d2 = dx * dx + dy * dy + dz * dz;
    return (d2 < thr2) ? 1u : 0u;
}

__global__ __launch_bounds__(256) void stats_kernel(
    const float* __restrict__ hws, const float* __restrict__ theta,
    int* __restrict__ acc)
{
    __shared__ float4 sh[S_];
    int bid = blockIdx.x;
    int b   = bid >> 8;
    int rem = bid & 255;
    int ct  = rem >> 3;
    int rb  = rem & 7;
    const float4* h4 = (const float4*)hws + (size_t)b * S_;
    for (int k = threadIdx.x; k < S_; k += 256) sh[k] = h4[k];
    __syncthreads();
    int lane = threadIdx.x & 63, wave = threadIdx.x >> 6;
    int j = ct * 64 + lane;
    float4 hj = sh[j];
    float maxd2 = __int_as_float(acc[b * 4 + 0]);
    float sig = 1.f / (1.f + expf(-theta[0]));
    float thr2 = sig * sig * maxd2;
    int s0 = rb * 256 + wave * 64;

    unsigned Rprev = (s0 > 0) ? computeR(sh, s0 - 1, hj.x, hj.y, hj.z, thr2) : 0u;
    unsigned m0 = 0u, m1 = 0u;
#pragma unroll
    for (int k = 0; k < 32; ++k)
        m0 |= computeR(sh, s0 + k, hj.x, hj.y, hj.z, thr2) << k;
#pragma unroll
    for (int k = 0; k < 32; ++k)
        m1 |= computeR(sh, s0 + 32 + k, hj.x, hj.y, hj.z, thr2) << k;
    unsigned Rnext = (s0 + 64 < S_) ? computeR(sh, s0 + 64, hj.x, hj.y, hj.z, thr2) : 0u;

    unsigned long long mask = ((unsigned long long)m1 << 32) | m0;
    int total = __popcll(mask);
    // vertical run starts: R[s] & ~R[s-1] & R[s+1]
    unsigned long long sp = (mask << 1) | (unsigned long long)Rprev;
    unsigned long long sn = (mask >> 1) | ((unsigned long long)Rnext << 63);
    int vert = __popcll(mask & ~sp & sn);
    // diag band: rows s with j - s in [1, 9]  -> bits [j-9-s0, j-1-s0]
    int lo = j - 9 - s0, hi = j - 1 - s0;
    unsigned long long bandm = 0ull;
    if (hi >= 0 && lo <= 63) {
        int l = lo < 0 ? 0 : lo;
        int h = hi > 63 ? 63 : hi;
        int len = h - l + 1;                     // <= 9, never 64
        bandm = ((1ull << len) - 1ull) << l;
    }
    int diag = __popcll(mask & bandm);

#pragma unroll
    for (int off = 32; off >= 1; off >>= 1) {
        total += __shfl_xor(total, off, 64);
        diag  += __shfl_xor(diag,  off, 64);
        vert  += __shfl_xor(vert,  off, 64);
    }
    __shared__ int wsum[4][3];
    if (lane == 0) { wsum[wave][0] = total; wsum[wave][1] = diag; wsum[wave][2] = vert; }
    __syncthreads();
    if (threadIdx.x == 0) {
        int t = 0, d = 0, v = 0;
        for (int w = 0; w < 4; ++w) { t += wsum[w][0]; d += wsum[w][1]; v += wsum[w][2]; }
        atomicAdd(&acc[b * 4 + 1], t);
        atomicAdd(&acc[b * 4 + 2], d);
        atomicAdd(&acc[b * 4 + 3], v);
    }
}

__global__ void finalize_kernel(const int* __restrict__ acc,
    const float* __restrict__ w3, const float* __restrict__ b3,
    float* __restrict__ out)
{
    int idx = blockIdx.x * 256 + threadIdx.x;    // 0..1023
    if (idx >= B_ * OUT_DIM) return;
    int b = idx >> 6, o = idx & 63;
    float total = (float)acc[b * 4 + 1];
    float diag  = (float)acc[b * 4 + 2];
    float vert  = (float)acc[b * 4 + 3];
    float rr  = total / (float)(S_ * S_);
    float det = diag / (total + 1e-6f);
    float lam = vert / (total + 1e-6f);
    // fp32 semantics to match the fp32 reference: log(1f + 1e-6f)
    float entr = -total * logf(1.0f + 1e-6f);
    float r = b3[o] + rr  * w3[0 * OUT_DIM + o]
                    + det * w3[1 * OUT_DIM + o]
                    + lam * w3[2 * OUT_DIM + o]
                    + entr * w3[3 * OUT_DIM + o];
    out[idx] = fmaxf(r, 0.f);
}

extern "C" void kernel_launch(void* const* d_in, const int* in_sizes, int n_in,
                              void* d_out, int out_size, void* d_ws, size_t ws_size,
                              hipStream_t stream) {
    const float* x     = (const float*)d_in[0];
    const float* theta = (const float*)d_in[1];
    const float* w1    = (const float*)d_in[2];
    const float* b1    = (const float*)d_in[3];
    const float* w2    = (const float*)d_in[4];
    const float* b2    = (const float*)d_in[5];
    const float* w3    = (const float*)d_in[6];
    const float* b3    = (const float*)d_in[7];
    float* out = (float*)d_out;
    float* hws = (float*)d_ws;
    int* acc = (int*)((char*)d_ws + (size_t)B_ * S_ * 4 * sizeof(float));

    hipLaunchKernelGGL(init_acc, dim3(1), dim3(64), 0, stream, acc);
    hipLaunchKernelGGL(embed_kernel, dim3(B_ * S_ / 4), dim3(256), 0, stream,
                       x, w1, b1, w2, b2, hws);
    hipLaunchKernelGGL(max_kernel, dim3(B_ * 256), dim3(256), 0, stream, hws, acc);
    hipLaunchKernelGGL(stats_kernel, dim3(B_ * 256), dim3(256), 0, stream, hws, theta, acc);
    hipLaunchKernelGGL(finalize_kernel, dim3(4), dim3(256), 0, stream, acc, w3, b3, out);
}

// Round 2
// 132.922 us; speedup vs baseline: 1.9443x; 1.9443x over previous
//
#include <hip/hip_runtime.h>
#include <math.h>

#define B_ 16
#define S_ 2048
#define IN_DIM 128
#define E2 6
#define E_ 3
#define OUT_DIM 64

// ws layout:
//   [0, B*S*4 floats)  : h padded to float4 (x,y,z,0)   = 524288 B
//   then 64 ints       : per batch {max_d2_bits, total, diag, vert}

// one wave per row: 64 lanes x float2 = 128 inputs. Block 0 also zeroes acc.
__global__ __launch_bounds__(256) void embed_kernel(
    const float* __restrict__ x, const float* __restrict__ w1,
    const float* __restrict__ b1, const float* __restrict__ w2,
    const float* __restrict__ b2, float* __restrict__ hws,
    int* __restrict__ acc)
{
    if (blockIdx.x == 0 && threadIdx.x < 64) acc[threadIdx.x] = 0;
    int wave = threadIdx.x >> 6;
    int lane = threadIdx.x & 63;
    int row  = blockIdx.x * 4 + wave;            // [0, B*S)
    const float2* x2 = (const float2*)(x + (size_t)row * IN_DIM);
    float2 xv = x2[lane];
    const float* w1a = w1 + (2 * lane) * E2;     // 12 contiguous floats
    float a[E2];
#pragma unroll
    for (int j = 0; j < E2; ++j)
        a[j] = xv.x * w1a[j] + xv.y * w1a[E2 + j];
#pragma unroll
    for (int j = 0; j < E2; ++j) {
#pragma unroll
        for (int off = 32; off >= 1; off >>= 1)
            a[j] += __shfl_xor(a[j], off, 64);
    }
    if (lane == 0) {
        float r[E2];
#pragma unroll
        for (int j = 0; j < E2; ++j) r[j] = fmaxf(a[j] + b1[j], 0.f);
        float h[E_];
#pragma unroll
        for (int e = 0; e < E_; ++e) {
            float s = b2[e];
#pragma unroll
            for (int j = 0; j < E2; ++j) s += r[j] * w2[j * E_ + e];
            h[e] = s;
        }
        ((float4*)hws)[row] = make_float4(h[0], h[1], h[2], 0.f);
    }
}

__device__ __forceinline__ float d2f(float4 a, float4 p) {
    float dx = a.x - p.x, dy = a.y - p.y, dz = a.z - p.z;
    return dx * dx + dy * dy + dz * dz;
}

// grid: B * 8 colBlocks * 8 rowSpans = 1024 blocks of 256.
// thread = one column j; sweeps 256 uniform rows (scalar-loadable).
__global__ __launch_bounds__(256) void max_kernel(
    const float4* __restrict__ h4, int* __restrict__ acc)
{
    int bid = blockIdx.x;
    int b  = bid >> 6;
    int cb = (bid >> 3) & 7;
    int rb = bid & 7;
    const float4* hb = h4 + (size_t)b * S_;
    int j = cb * 256 + threadIdx.x;
    float4 hj = hb[j];
    int r0 = rb * 256;
    float m = 0.f;
    for (int c = 0; c < 256; c += 8) {
        float4 buf[8];
#pragma unroll
        for (int k = 0; k < 8; ++k) buf[k] = hb[r0 + c + k];   // uniform -> s_load
#pragma unroll
        for (int k = 0; k < 8; ++k)
            m = fmaxf(m, d2f(hj, buf[k]));
    }
#pragma unroll
    for (int off = 32; off >= 1; off >>= 1)
        m = fmaxf(m, __shfl_xor(m, off, 64));
    __shared__ float wmax[4];
    int lane = threadIdx.x & 63, wave = threadIdx.x >> 6;
    if (lane == 0) wmax[wave] = m;
    __syncthreads();
    if (threadIdx.x == 0) {
        float mm = fmaxf(fmaxf(wmax[0], wmax[1]), fmaxf(wmax[2], wmax[3]));
        atomicMax(&acc[b * 4 + 0], __float_as_int(mm));  // d2>=0: int order == float order
    }
}

__global__ __launch_bounds__(256) void stats_kernel(
    const float4* __restrict__ h4, const float* __restrict__ theta,
    int* __restrict__ acc)
{
    int bid = blockIdx.x;
    int b  = bid >> 6;
    int cb = (bid >> 3) & 7;
    int rb = bid & 7;
    const float4* hb = h4 + (size_t)b * S_;
    int j = cb * 256 + threadIdx.x;
    float4 hj = hb[j];
    float maxd2 = __int_as_float(acc[b * 4 + 0]);
    float sig = 1.f / (1.f + expf(-theta[0]));
    float thr2 = sig * sig * maxd2;
    int r0 = rb * 256;

    unsigned prev = (r0 > 0) ? (d2f(hj, hb[r0 - 1]) < thr2 ? 1u : 0u) : 0u;
    unsigned pend = 0u;
    int total = 0, diag = 0, vert = 0;

    for (int s0 = r0; s0 < r0 + 256; s0 += 64) {
        unsigned m0 = 0u, m1 = 0u;
        for (int c = 0; c < 64; c += 8) {
            float4 buf[8];
#pragma unroll
            for (int k = 0; k < 8; ++k) buf[k] = hb[s0 + c + k];   // uniform -> s_load
#pragma unroll
            for (int k = 0; k < 8; ++k) {
                unsigned r = (d2f(hj, buf[k]) < thr2) ? 1u : 0u;
                int bit = c + k;
                if (bit < 32) m0 |= r << bit;
                else          m1 |= r << (bit - 32);
            }
        }
        unsigned long long m = ((unsigned long long)m1 << 32) | m0;
        total += __popcll(m);
        // vertical run starts: R[i] & ~R[i-1] & R[i+1]
        unsigned long long notprev = ~((m << 1) | (unsigned long long)prev);
        vert += __popcll(m & notprev & (m >> 1));        // bits 0..62 resolved here
        vert += (int)(pend & (unsigned)(m & 1ull));      // resolve prior segment's bit63
        pend  = (unsigned)((m & notprev) >> 63);
        prev  = (unsigned)(m >> 63);
        // diag band: rows s with j-s in [1,9] -> bits [j-9-s0, j-1-s0]
        int lo = j - 9 - s0, hi = j - 1 - s0;
        if (hi >= 0 && lo <= 63) {
            int l = lo < 0 ? 0 : lo;
            int h = hi > 63 ? 63 : hi;
            unsigned long long bandm = ((1ull << (h - l + 1)) - 1ull) << l;
            diag += __popcll(m & bandm);
        }
    }
    if (r0 + 256 < S_) {
        unsigned nxt = (d2f(hj, hb[r0 + 256]) < thr2) ? 1u : 0u;
        vert += (int)(pend & nxt);
    }

#pragma unroll
    for (int off = 32; off >= 1; off >>= 1) {
        total += __shfl_xor(total, off, 64);
        diag  += __shfl_xor(diag,  off, 64);
        vert  += __shfl_xor(vert,  off, 64);
    }
    __shared__ int wsum[4][3];
    int lane = threadIdx.x & 63, wave = threadIdx.x >> 6;
    if (lane == 0) { wsum[wave][0] = total; wsum[wave][1] = diag; wsum[wave][2] = vert; }
    __syncthreads();
    if (threadIdx.x == 0) {
        int t = 0, d = 0, v = 0;
#pragma unroll
        for (int w = 0; w < 4; ++w) { t += wsum[w][0]; d += wsum[w][1]; v += wsum[w][2]; }
        atomicAdd(&acc[b * 4 + 1], t);
        atomicAdd(&acc[b * 4 + 2], d);
        atomicAdd(&acc[b * 4 + 3], v);
    }
}

__global__ void finalize_kernel(const int* __restrict__ acc,
    const float* __restrict__ w3, const float* __restrict__ b3,
    float* __restrict__ out)
{
    int idx = blockIdx.x * 256 + threadIdx.x;    // 0..1023
    if (idx >= B_ * OUT_DIM) return;
    int b = idx >> 6, o = idx & 63;
    float total = (float)acc[b * 4 + 1];
    float diag  = (float)acc[b * 4 + 2];
    float vert  = (float)acc[b * 4 + 3];
    float rr  = total / (float)(S_ * S_);
    float det = diag / (total + 1e-6f);
    float lam = vert / (total + 1e-6f);
    float entr = -total * logf(1.0f + 1e-6f);    // fp32 semantics (verified absmax 0.0)
    float r = b3[o] + rr  * w3[0 * OUT_DIM + o]
                    + det * w3[1 * OUT_DIM + o]
                    + lam * w3[2 * OUT_DIM + o]
                    + entr * w3[3 * OUT_DIM + o];
    out[idx] = fmaxf(r, 0.f);
}

extern "C" void kernel_launch(void* const* d_in, const int* in_sizes, int n_in,
                              void* d_out, int out_size, void* d_ws, size_t ws_size,
                              hipStream_t stream) {
    const float* x     = (const float*)d_in[0];
    const float* theta = (const float*)d_in[1];
    const float* w1    = (const float*)d_in[2];
    const float* b1    = (const float*)d_in[3];
    const float* w2    = (const float*)d_in[4];
    const float* b2    = (const float*)d_in[5];
    const float* w3    = (const float*)d_in[6];
    const float* b3    = (const float*)d_in[7];
    float* out = (float*)d_out;
    float* hws = (float*)d_ws;
    int* acc = (int*)((char*)d_ws + (size_t)B_ * S_ * 4 * sizeof(float));

    hipLaunchKernelGGL(embed_kernel, dim3(B_ * S_ / 4), dim3(256), 0, stream,
                       x, w1, b1, w2, b2, hws, acc);
    hipLaunchKernelGGL(max_kernel, dim3(B_ * 64), dim3(256), 0, stream,
                       (const float4*)hws, acc);
    hipLaunchKernelGGL(stats_kernel, dim3(B_ * 64), dim3(256), 0, stream,
                       (const float4*)hws, theta, acc);
    hipLaunchKernelGGL(finalize_kernel, dim3(4), dim3(256), 0, stream, acc, w3, b3, out);
}